// Round 3
// baseline (1031.360 us; speedup 1.0000x reference)
//
#include <hip/hip_runtime.h>

// Scatter-mean, three-tier strategy by workspace size.
//
//  Tier B (ws >= ~261MB): bin-partition + LDS-resident bin reduce.
//    R1/R2 established: fully-random 512B access over 256MB runs at
//    ~0.7-0.75 TB/s in BOTH directions (gather reads 393us; permute writes
//    385us, atomic-free). The lever left is the randomness radius: partition
//    edges into K=782 bins of 64 nodes. Pass-1 writes become 782
//    quasi-sequential streams (open DRAM row frontiers, L2 write-combine);
//    pass-2 is one block per bin: stream rows sequentially, accumulate into
//    a 33KB LDS accumulator (64 nodes x 128 f32 + counts), divide, write.
//    Traffic ~800MB => predicted ~190-250us total.
//    Falsifier: if copy_kernel stays ~385us, stream-count doesn't matter and
//    the 512B-granule floor is fundamental -> revert to gather.
//
//  Tier G (ws >= ~13MB): verified bucket-gather baseline (393.6us).
//  Tier A: atomic fallback.
//
// E=500000, D=128, N=50000.  R=64 nodes/bin, K=(N+63)/64=782.

#define D_DIM 128
#define DV    32     // float4 chunks per row
#define CAP   64
#define RBIN  64     // nodes per bin (power of 2)

typedef float f32x4 __attribute__((ext_vector_type(4)));

// ===================== Tier B kernels =====================

__global__ void count_bins_kernel(const int* __restrict__ index,
                                  int* __restrict__ bin_cnt, int E) {
    int e = blockIdx.x * blockDim.x + threadIdx.x;
    if (e < E) atomicAdd(&bin_cnt[index[e] >> 6], 1);
}

// Single-block exclusive scan over K bin counts -> bin_cursor (= bin base).
__global__ void scan_bins_kernel(const int* __restrict__ bin_cnt,
                                 int* __restrict__ bin_cursor, int K) {
    __shared__ int s[256];
    __shared__ int carry;
    int tid = threadIdx.x;
    if (tid == 0) carry = 0;
    __syncthreads();
    for (int base = 0; base < K; base += 256) {
        int i = base + tid;
        int v = (i < K) ? bin_cnt[i] : 0;
        s[tid] = v;
        __syncthreads();
        for (int d = 1; d < 256; d <<= 1) {
            int t = (tid >= d) ? s[tid - d] : 0;
            __syncthreads();
            s[tid] += t;
            __syncthreads();
        }
        if (i < K) bin_cursor[i] = carry + s[tid] - v;   // exclusive prefix
        __syncthreads();
        if (tid == 255) carry += s[255];
        __syncthreads();
    }
}

// One thread per edge, full-wave atomics (proven-fast pattern).
// Assigns each edge a slot within its bin's contiguous range and records
// the owning node of each slot. After this, bin_cursor[b] == segment END.
__global__ void dst_kernel(const int* __restrict__ index,
                           int* __restrict__ bin_cursor,
                           int* __restrict__ dst,
                           int* __restrict__ binned_node, int E) {
    int e = blockIdx.x * blockDim.x + threadIdx.x;
    if (e >= E) return;
    int idx = index[e];
    int slot = atomicAdd(&bin_cursor[idx >> 6], 1);
    dst[e] = slot;
    binned_node[slot] = idx;
}

// Streaming permute copy: half-wave (32 lanes x float4 = 512B) per row,
// 2 independent rows per thread. Sequential nt-reads of msg; writes land in
// 782 quasi-sequential bin streams (the experiment of this round).
__global__ __launch_bounds__(256)
void copy_kernel(const float* __restrict__ msg,
                 const int* __restrict__ dst,
                 float* __restrict__ binned, int E) {
    int t = blockIdx.x * blockDim.x + threadIdx.x;
    int h = t >> 5;
    int halfE = (E + 1) >> 1;
    if (h >= halfE) return;
    int sub = threadIdx.x & 31;

    const f32x4* m4 = reinterpret_cast<const f32x4*>(msg);
    f32x4* b4 = reinterpret_cast<f32x4*>(binned);

    int e0 = h;
    int e1 = h + halfE;
    int d0 = dst[e0];
    f32x4 v0 = __builtin_nontemporal_load(&m4[(size_t)e0 * DV + sub]);
    if (e1 < E) {
        int d1 = dst[e1];
        f32x4 v1 = __builtin_nontemporal_load(&m4[(size_t)e1 * DV + sub]);
        b4[(size_t)d0 * DV + sub] = v0;
        b4[(size_t)d1 * DV + sub] = v1;
    } else {
        b4[(size_t)d0 * DV + sub] = v0;
    }
}

// One block per bin: stream the bin's rows (fully sequential reads),
// accumulate into LDS (64 nodes x 128 f32 + 64 counts = 33KB), then
// divide by count and write the bin's 64 output rows.
__global__ __launch_bounds__(256)
void bin_reduce_kernel(const float* __restrict__ binned,
                       const int* __restrict__ binned_node,
                       const int* __restrict__ bin_cnt,
                       const int* __restrict__ bin_cursor,
                       float* __restrict__ out, int N) {
    __shared__ float acc[RBIN * D_DIM];
    __shared__ int   lcnt[RBIN];

    int b = blockIdx.x;
    int tid = threadIdx.x;
    int hw  = tid >> 5;          // half-wave id 0..7
    int sub = tid & 31;          // float4 chunk within row

    for (int i = tid; i < RBIN * D_DIM; i += 256) acc[i] = 0.0f;
    if (tid < RBIN) lcnt[tid] = 0;
    __syncthreads();

    int cnt   = bin_cnt[b];
    int start = bin_cursor[b] - cnt;     // cursor holds segment end

    const f32x4* b4 = reinterpret_cast<const f32x4*>(binned);

    int last = cnt - 1;
    for (int r0 = hw * 4; r0 < cnt; r0 += 32) {
        // batch 4 rows per half-wave for MLP; clamp OOB rows to 'last'
        int r0c = r0 + 0 < cnt ? r0 + 0 : last;
        int r1c = r0 + 1 < cnt ? r0 + 1 : last;
        int r2c = r0 + 2 < cnt ? r0 + 2 : last;
        int r3c = r0 + 3 < cnt ? r0 + 3 : last;
        f32x4 v0 = __builtin_nontemporal_load(&b4[(size_t)(start + r0c) * DV + sub]);
        f32x4 v1 = __builtin_nontemporal_load(&b4[(size_t)(start + r1c) * DV + sub]);
        f32x4 v2 = __builtin_nontemporal_load(&b4[(size_t)(start + r2c) * DV + sub]);
        f32x4 v3 = __builtin_nontemporal_load(&b4[(size_t)(start + r3c) * DV + sub]);
        int n0 = binned_node[start + r0c] & (RBIN - 1);
        int n1 = binned_node[start + r1c] & (RBIN - 1);
        int n2 = binned_node[start + r2c] & (RBIN - 1);
        int n3 = binned_node[start + r3c] & (RBIN - 1);
        if (r0 + 0 < cnt) {
            float* a = &acc[n0 * D_DIM + sub * 4];
            atomicAdd(a + 0, v0.x); atomicAdd(a + 1, v0.y);
            atomicAdd(a + 2, v0.z); atomicAdd(a + 3, v0.w);
            if (sub == 0) atomicAdd(&lcnt[n0], 1);
        }
        if (r0 + 1 < cnt) {
            float* a = &acc[n1 * D_DIM + sub * 4];
            atomicAdd(a + 0, v1.x); atomicAdd(a + 1, v1.y);
            atomicAdd(a + 2, v1.z); atomicAdd(a + 3, v1.w);
            if (sub == 0) atomicAdd(&lcnt[n1], 1);
        }
        if (r0 + 2 < cnt) {
            float* a = &acc[n2 * D_DIM + sub * 4];
            atomicAdd(a + 0, v2.x); atomicAdd(a + 1, v2.y);
            atomicAdd(a + 2, v2.z); atomicAdd(a + 3, v2.w);
            if (sub == 0) atomicAdd(&lcnt[n2], 1);
        }
        if (r0 + 3 < cnt) {
            float* a = &acc[n3 * D_DIM + sub * 4];
            atomicAdd(a + 0, v3.x); atomicAdd(a + 1, v3.y);
            atomicAdd(a + 2, v3.z); atomicAdd(a + 3, v3.w);
            if (sub == 0) atomicAdd(&lcnt[n3], 1);
        }
    }
    __syncthreads();

    // epilogue: each half-wave writes 8 of the bin's 64 nodes
    f32x4* o4 = reinterpret_cast<f32x4*>(out);
    int gbase = b << 6;
    for (int ln = hw; ln < RBIN; ln += 8) {
        int g = gbase + ln;
        if (g >= N) break;
        float inv = 1.0f / fmaxf((float)lcnt[ln], 1.0f);
        const float* a = &acc[ln * D_DIM + sub * 4];
        f32x4 o = {a[0] * inv, a[1] * inv, a[2] * inv, a[3] * inv};
        __builtin_nontemporal_store(o, &o4[(size_t)g * DV + sub]);
    }
}

// ===================== Tier G: verified bucket-gather baseline =====================

__global__ void bucket_kernel(const int* __restrict__ index,
                              int* __restrict__ cursor,
                              int* __restrict__ bucket,
                              int E) {
    int e = blockIdx.x * blockDim.x + threadIdx.x;
    if (e >= E) return;
    int idx = index[e];
    int pos = atomicAdd(&cursor[idx], 1);
    if (pos < CAP) bucket[(size_t)idx * CAP + pos] = e;
}

__global__ __launch_bounds__(256, 8)
void gather_kernel(const float* __restrict__ msg,
                   const int* __restrict__ cursor,
                   const int* __restrict__ bucket,
                   float* __restrict__ out,
                   int N) {
    int gtid = blockIdx.x * blockDim.x + threadIdx.x;
    int node = gtid >> 6;
    if (node >= N) return;
    int lane = threadIdx.x & 63;
    int half = lane >> 5;
    int sub  = lane & 31;

    int cnt_true = cursor[node];
    int cnt = cnt_true < CAP ? cnt_true : CAP;

    int eid = (lane < cnt) ? bucket[(size_t)node * CAP + lane] : 0;

    const float4* m4 = reinterpret_cast<const float4*>(msg);
    float4 acc = make_float4(0.0f, 0.0f, 0.0f, 0.0f);

    for (int j = 0; j < cnt; j += 8) {
        int i0 = j + 0 + half, i1 = j + 2 + half, i2 = j + 4 + half, i3 = j + 6 + half;
        int e0 = __shfl(eid, i0);
        int e1 = __shfl(eid, i1);
        int e2 = __shfl(eid, i2);
        int e3 = __shfl(eid, i3);
        float4 v0 = m4[(size_t)e0 * 32 + sub];
        float4 v1 = m4[(size_t)e1 * 32 + sub];
        float4 v2 = m4[(size_t)e2 * 32 + sub];
        float4 v3 = m4[(size_t)e3 * 32 + sub];
        if (i0 < cnt) { acc.x += v0.x; acc.y += v0.y; acc.z += v0.z; acc.w += v0.w; }
        if (i1 < cnt) { acc.x += v1.x; acc.y += v1.y; acc.z += v1.z; acc.w += v1.w; }
        if (i2 < cnt) { acc.x += v2.x; acc.y += v2.y; acc.z += v2.z; acc.w += v2.w; }
        if (i3 < cnt) { acc.x += v3.x; acc.y += v3.y; acc.z += v3.z; acc.w += v3.w; }
    }

    acc.x += __shfl_xor(acc.x, 32);
    acc.y += __shfl_xor(acc.y, 32);
    acc.z += __shfl_xor(acc.z, 32);
    acc.w += __shfl_xor(acc.w, 32);

    float inv = 1.0f / fmaxf((float)cnt_true, 1.0f);
    acc.x *= inv; acc.y *= inv; acc.z *= inv; acc.w *= inv;

    if (half == 0) {
        reinterpret_cast<float4*>(out)[(size_t)node * 32 + sub] = acc;
    }
}

// ===================== Tier A: atomic fallback =====================

__global__ void scatter_add_kernel(const float* __restrict__ msg,
                                   const int* __restrict__ index,
                                   float* __restrict__ out,
                                   float* __restrict__ counts,
                                   int E) {
    int i = blockIdx.x * blockDim.x + threadIdx.x;
    int total = E * DV;
    if (i >= total) return;
    int e = i / DV;
    int c = i & (DV - 1);
    int idx = index[e];
    float4 v = reinterpret_cast<const float4*>(msg)[(size_t)e * DV + c];
    float* dstp = out + (size_t)idx * D_DIM + c * 4;
    atomicAdd(dstp + 0, v.x);
    atomicAdd(dstp + 1, v.y);
    atomicAdd(dstp + 2, v.z);
    atomicAdd(dstp + 3, v.w);
    if (c == 0) atomicAdd(&counts[idx], 1.0f);
}

__global__ void divide_kernel(float* __restrict__ out,
                              const float* __restrict__ counts,
                              int N) {
    int i = blockIdx.x * blockDim.x + threadIdx.x;
    int total = N * DV;
    if (i >= total) return;
    int n = i / DV;
    float inv = 1.0f / fmaxf(counts[n], 1.0f);
    float4* p = reinterpret_cast<float4*>(out) + i;
    float4 v = *p;
    v.x *= inv; v.y *= inv; v.z *= inv; v.w *= inv;
    *p = v;
}

// ===================== launcher =====================

extern "C" void kernel_launch(void* const* d_in, const int* in_sizes, int n_in,
                              void* d_out, int out_size, void* d_ws, size_t ws_size,
                              hipStream_t stream) {
    const float* msg   = (const float*)d_in[0];
    const int*   index = (const int*)d_in[1];
    float* out = (float*)d_out;

    int E = in_sizes[0] / D_DIM;   // 500000
    int N = out_size / D_DIM;      // 50000
    int K = (N + RBIN - 1) / RBIN; // 782 bins

    // Tier B workspace: binned rows + dst + binned_node + bin_cnt + bin_cursor
    size_t needB = (size_t)E * D_DIM * sizeof(float)
                 + ((size_t)2 * E + 2 * (size_t)K + 16) * sizeof(int);
    // Tier G workspace: cursor + buckets
    size_t needG = (size_t)N * sizeof(int) + (size_t)N * CAP * sizeof(int);

    if (ws_size >= needB) {
        float* binned      = (float*)d_ws;
        int*   dst         = (int*)(binned + (size_t)E * D_DIM);
        int*   binned_node = dst + E;
        int*   bin_cnt     = binned_node + E;
        int*   bin_cursor  = bin_cnt + K;

        (void)hipMemsetAsync(bin_cnt, 0, (size_t)K * sizeof(int), stream);

        count_bins_kernel<<<(E + 255) / 256, 256, 0, stream>>>(index, bin_cnt, E);
        scan_bins_kernel<<<1, 256, 0, stream>>>(bin_cnt, bin_cursor, K);
        dst_kernel<<<(E + 255) / 256, 256, 0, stream>>>(index, bin_cursor, dst,
                                                        binned_node, E);

        int halfE = (E + 1) / 2;
        int grid_c = (halfE * 32 + 255) / 256;
        copy_kernel<<<grid_c, 256, 0, stream>>>(msg, dst, binned, E);

        bin_reduce_kernel<<<K, 256, 0, stream>>>(binned, binned_node, bin_cnt,
                                                 bin_cursor, out, N);
    } else if (ws_size >= needG) {
        int* cursor = (int*)d_ws;
        int* bucket = cursor + N;

        (void)hipMemsetAsync(cursor, 0, (size_t)N * sizeof(int), stream);
        {
            int block = 256;
            int grid = (E + block - 1) / block;
            bucket_kernel<<<grid, block, 0, stream>>>(index, cursor, bucket, E);
        }
        {
            int block = 256;
            int nodes_per_block = block / 64;
            int grid = (N + nodes_per_block - 1) / nodes_per_block;
            gather_kernel<<<grid, block, 0, stream>>>(msg, cursor, bucket, out, N);
        }
    } else {
        float* counts = (float*)d_ws;
        (void)hipMemsetAsync(out, 0, (size_t)out_size * sizeof(float), stream);
        (void)hipMemsetAsync(counts, 0, (size_t)N * sizeof(float), stream);
        {
            int total = E * DV;
            int block = 256;
            int grid = (total + block - 1) / block;
            scatter_add_kernel<<<grid, block, 0, stream>>>(msg, index, out, counts, E);
        }
        {
            int total = N * DV;
            int block = 256;
            int grid = (total + block - 1) / block;
            divide_kernel<<<grid, block, 0, stream>>>(out, counts, N);
        }
    }
}